// Round 1
// baseline (573.582 us; speedup 1.0000x reference)
//
#include <hip/hip_runtime.h>

typedef unsigned short u16;
typedef __bf16 bf16_t;
typedef bf16_t bf16x8 __attribute__((ext_vector_type(8)));
typedef float f32x4 __attribute__((ext_vector_type(4)));
typedef u16 u16x8 __attribute__((ext_vector_type(8)));

#define B_     4
#define N_     2048
#define DIM_   1024
#define HEADS_ 16
#define DH_    64
#define INNER_ 1024
#define QKV3_  3072
#define SCALE_ 0.125f

__device__ __forceinline__ u16 f2bf(float f) {
  union { float f; unsigned u; } v; v.f = f;
  unsigned r = v.u + 0x7FFFu + ((v.u >> 16) & 1u);
  return (u16)(r >> 16);
}

// ---------------- x fp32 -> bf16 (vectorized, G13) ----------------
__global__ __launch_bounds__(256) void cvt_f32_bf16(const float* __restrict__ in,
                                                    u16* __restrict__ out, int n8) {
  int i = blockIdx.x * 256 + threadIdx.x;
  if (i < n8) {
    const float4* p = (const float4*)(in + (size_t)i * 8);
    float4 a = p[0], b = p[1];
    u16x8 o;
    o[0] = f2bf(a.x); o[1] = f2bf(a.y); o[2] = f2bf(a.z); o[3] = f2bf(a.w);
    o[4] = f2bf(b.x); o[5] = f2bf(b.y); o[6] = f2bf(b.z); o[7] = f2bf(b.w);
    *(u16x8*)(out + (size_t)i * 8) = o;
  }
}

// ---------------- w [K][N] fp32 -> wT [N][K] bf16 ----------------
__global__ __launch_bounds__(256) void transp_w(const float* __restrict__ in,
                                                u16* __restrict__ out, int Kd, int Nd) {
  __shared__ float t[32][33];
  int n0 = blockIdx.x * 32, k0 = blockIdx.y * 32;
  int tx = threadIdx.x & 31, ty = threadIdx.x >> 5;   // 256 threads: 32x8
#pragma unroll
  for (int i = 0; i < 4; i++)
    t[ty + i * 8][tx] = in[(size_t)(k0 + ty + i * 8) * Nd + n0 + tx];
  __syncthreads();
#pragma unroll
  for (int i = 0; i < 4; i++)
    out[(size_t)(n0 + ty + i * 8) * Kd + k0 + tx] = f2bf(t[tx][ty + i * 8]);
}

// ---------------- V slice of qkv -> vT [b,h,d,n] bf16 ----------------
__global__ __launch_bounds__(256) void transp_v(const u16* __restrict__ qkv,
                                                u16* __restrict__ vT) {
  __shared__ u16 t[32][33];
  int bh = blockIdx.z; int b = bh >> 4, h = bh & 15;
  int n0 = blockIdx.x * 32, d0 = blockIdx.y * 32;
  int tx = threadIdx.x & 31, ty = threadIdx.x >> 5;
#pragma unroll
  for (int i = 0; i < 4; i++)
    t[ty + i * 8][tx] =
        qkv[(size_t)(b * N_ + n0 + ty + i * 8) * QKV3_ + 2 * INNER_ + h * DH_ + d0 + tx];
  __syncthreads();
#pragma unroll
  for (int i = 0; i < 4; i++)
    vT[((size_t)bh * DH_ + d0 + ty + i * 8) * N_ + n0 + tx] = t[tx][ty + i * 8];
}

// ---------------- GEMM: C[M][N] = A[M][K](bf16) @ BT[N][K](bf16)^T ----------------
// 128x128 tile, BK=64, 256 threads = 4 waves (2x2), 4x4 16x16x32 frags/wave.
// LDS XOR-swizzle byte ^= ((row&7)<<4) on both write and read (G4).
template <int F32OUT>
__global__ __launch_bounds__(256) void gemm_bt(const u16* __restrict__ A,
                                               const u16* __restrict__ BT,
                                               void* __restrict__ Cp,
                                               const float* __restrict__ bias,
                                               int M, int N, int K) {
  __shared__ alignas(16) u16 ldsA[128 * 64];
  __shared__ alignas(16) u16 ldsB[128 * 64];
  const int tid = threadIdx.x;
  const int lane = tid & 63, wid = tid >> 6;
  const int l16 = lane & 15, lg = lane >> 4;
  const int ntiles = N >> 7;
  const int tm = blockIdx.x / ntiles, tn = blockIdx.x % ntiles;
  const int m0 = tm << 7, n0 = tn << 7;
  const int wr = wid >> 1, wc = wid & 1;

  f32x4 acc[4][4];
#pragma unroll
  for (int i = 0; i < 4; i++)
#pragma unroll
    for (int j = 0; j < 4; j++) acc[i][j] = f32x4{0.f, 0.f, 0.f, 0.f};

  for (int k0 = 0; k0 < K; k0 += 64) {
#pragma unroll
    for (int i = 0; i < 4; i++) {
      int c = i * 256 + tid;
      int row = c >> 3, slot = c & 7;
      uint4 va = *(const uint4*)(A  + (size_t)(m0 + row) * K + k0 + slot * 8);
      uint4 vb = *(const uint4*)(BT + (size_t)(n0 + row) * K + k0 + slot * 8);
      int off = row * 128 + ((slot * 16) ^ ((row & 7) << 4));
      *(uint4*)((char*)ldsA + off) = va;
      *(uint4*)((char*)ldsB + off) = vb;
    }
    __syncthreads();

    bf16x8 bf[4][2];
#pragma unroll
    for (int n = 0; n < 4; n++) {
      int row = wc * 64 + n * 16 + l16;
      int rb = row * 128, swz = (row & 7) << 4;
      bf[n][0] = *(const bf16x8*)((char*)ldsB + rb + ((lg * 16) ^ swz));
      bf[n][1] = *(const bf16x8*)((char*)ldsB + rb + ((64 + lg * 16) ^ swz));
    }
#pragma unroll
    for (int mm = 0; mm < 4; mm++) {
      int row = wr * 64 + mm * 16 + l16;
      int rb = row * 128, swz = (row & 7) << 4;
      bf16x8 af0 = *(const bf16x8*)((char*)ldsA + rb + ((lg * 16) ^ swz));
      bf16x8 af1 = *(const bf16x8*)((char*)ldsA + rb + ((64 + lg * 16) ^ swz));
#pragma unroll
      for (int n = 0; n < 4; n++) {
        acc[mm][n] = __builtin_amdgcn_mfma_f32_16x16x32_bf16(af0, bf[n][0], acc[mm][n], 0, 0, 0);
        acc[mm][n] = __builtin_amdgcn_mfma_f32_16x16x32_bf16(af1, bf[n][1], acc[mm][n], 0, 0, 0);
      }
    }
    __syncthreads();
  }

  // C/D layout: row=(lane>>4)*4+reg, col=lane&15 (verified m89/m91)
#pragma unroll
  for (int mm = 0; mm < 4; mm++) {
#pragma unroll
    for (int n = 0; n < 4; n++) {
      int row = m0 + wr * 64 + mm * 16 + lg * 4;
      int col = n0 + wc * 64 + n * 16 + l16;
#pragma unroll
      for (int j = 0; j < 4; j++) {
        if (F32OUT)
          ((float*)Cp)[(size_t)(row + j) * N + col] = acc[mm][n][j] + bias[col];
        else
          ((u16*)Cp)[(size_t)(row + j) * N + col] = f2bf(acc[mm][n][j]);
      }
    }
  }
}

// ---------------- Flash attention ----------------
// grid: bh*32+qt (2048 blocks), 256 threads = 4 waves, each wave owns 16 q-rows.
// Q/K fragments read directly from qkv (L2-resident); V from vT.
// P relayout via per-wave swizzled LDS buffer.
__global__ __launch_bounds__(256) void attn_fwd(const u16* __restrict__ qkv,
                                                const u16* __restrict__ vT,
                                                u16* __restrict__ abuf) {
  __shared__ alignas(16) u16 plds[4][16 * 64];
  const int tid = threadIdx.x;
  const int lane = tid & 63, wid = tid >> 6;
  const int l16 = lane & 15, lg = lane >> 4;
  const int bh = blockIdx.x >> 5;
  const int qt = blockIdx.x & 31;
  const int b = bh >> 4, h = bh & 15;
  const int q0 = qt * 64 + wid * 16;

  const u16* qrow = qkv + (size_t)(b * N_ + q0 + l16) * QKV3_ + h * DH_;
  bf16x8 qf0 = *(const bf16x8*)(qrow + lg * 8);
  bf16x8 qf1 = *(const bf16x8*)(qrow + 32 + lg * 8);

  const u16* kbase = qkv + (size_t)(b * N_) * QKV3_ + INNER_ + h * DH_;
  const u16* vbase = vT + (size_t)bh * DH_ * N_;

  float mrow[4], lrow[4];
  f32x4 acc[4];
#pragma unroll
  for (int j = 0; j < 4; j++) { mrow[j] = -1e30f; lrow[j] = 0.f; }
#pragma unroll
  for (int d = 0; d < 4; d++) acc[d] = f32x4{0.f, 0.f, 0.f, 0.f};

  char* pb = (char*)&plds[wid][0];

  for (int kt = 0; kt < N_ / 64; ++kt) {
    const int key0 = kt * 64;
    f32x4 s[4];
#pragma unroll
    for (int kc = 0; kc < 4; kc++) {
      const u16* kr = kbase + (size_t)(key0 + kc * 16 + l16) * QKV3_;
      bf16x8 kf0 = *(const bf16x8*)(kr + lg * 8);
      bf16x8 kf1 = *(const bf16x8*)(kr + 32 + lg * 8);
      f32x4 c = f32x4{0.f, 0.f, 0.f, 0.f};
      c = __builtin_amdgcn_mfma_f32_16x16x32_bf16(qf0, kf0, c, 0, 0, 0);
      c = __builtin_amdgcn_mfma_f32_16x16x32_bf16(qf1, kf1, c, 0, 0, 0);
#pragma unroll
      for (int j = 0; j < 4; j++) c[j] *= SCALE_;
      s[kc] = c;
    }
    // row stats over 64 keys: local over kc, then 16-lane-group shfl reduce
    float alpha[4], psum[4];
#pragma unroll
    for (int j = 0; j < 4; j++) {
      float t = fmaxf(fmaxf(s[0][j], s[1][j]), fmaxf(s[2][j], s[3][j]));
#pragma unroll
      for (int off = 1; off < 16; off <<= 1) t = fmaxf(t, __shfl_xor(t, off));
      float mn = fmaxf(mrow[j], t);
      alpha[j] = __expf(mrow[j] - mn);
      mrow[j] = mn;
      psum[j] = 0.f;
    }
    // P = exp(s - m), write bf16 to swizzled LDS
#pragma unroll
    for (int kc = 0; kc < 4; kc++) {
#pragma unroll
      for (int j = 0; j < 4; j++) {
        float p = __expf(s[kc][j] - mrow[j]);
        psum[j] += p;
        int row = lg * 4 + j;
        int off = row * 128 + ((((kc * 16 + l16) * 2)) ^ ((row & 7) << 4));
        *(u16*)(pb + off) = f2bf(p);
      }
    }
#pragma unroll
    for (int j = 0; j < 4; j++) {
      float t = psum[j];
#pragma unroll
      for (int off = 1; off < 16; off <<= 1) t += __shfl_xor(t, off);
      lrow[j] = lrow[j] * alpha[j] + t;
    }
#pragma unroll
    for (int d = 0; d < 4; d++)
#pragma unroll
      for (int j = 0; j < 4; j++) acc[d][j] *= alpha[j];

    __syncthreads();

    // PV: A = P (from LDS, A-frag row=l16, k=8*lg+j), B = V^T fragments
    bf16x8 pa0 = *(const bf16x8*)(pb + l16 * 128 + ((lg * 16) ^ ((l16 & 7) << 4)));
    bf16x8 pa1 = *(const bf16x8*)(pb + l16 * 128 + ((64 + lg * 16) ^ ((l16 & 7) << 4)));
#pragma unroll
    for (int d = 0; d < 4; d++) {
      const u16* vr = vbase + (size_t)(d * 16 + l16) * N_ + key0;
      bf16x8 vf0 = *(const bf16x8*)(vr + lg * 8);
      bf16x8 vf1 = *(const bf16x8*)(vr + 32 + lg * 8);
      acc[d] = __builtin_amdgcn_mfma_f32_16x16x32_bf16(pa0, vf0, acc[d], 0, 0, 0);
      acc[d] = __builtin_amdgcn_mfma_f32_16x16x32_bf16(pa1, vf1, acc[d], 0, 0, 0);
    }
    __syncthreads();
  }

  // epilogue: normalize, write attention out [b,n,h*d] bf16
#pragma unroll
  for (int j = 0; j < 4; j++) {
    float inv = 1.f / lrow[j];
    size_t row = (size_t)(b * N_ + q0 + lg * 4 + j);
#pragma unroll
    for (int d = 0; d < 4; d++)
      abuf[row * INNER_ + h * DH_ + d * 16 + l16] = f2bf(acc[d][j] * inv);
  }
}

extern "C" void kernel_launch(void* const* d_in, const int* in_sizes, int n_in,
                              void* d_out, int out_size, void* d_ws, size_t ws_size,
                              hipStream_t stream) {
  const float* x     = (const float*)d_in[0];
  const float* w_qkv = (const float*)d_in[1];
  const float* w_out = (const float*)d_in[2];
  const float* b_out = (const float*)d_in[3];
  float* out = (float*)d_out;

  char* ws = (char*)d_ws;
  u16* xb    = (u16*)(ws);                          // 16 MiB  [8192][1024]
  u16* wqkvT = (u16*)(ws + (size_t)(16 << 20));     //  6 MiB  [3072][1024]
  u16* woutT = (u16*)(ws + (size_t)(22 << 20));     //  2 MiB  [1024][1024]
  u16* qkv   = (u16*)(ws + (size_t)(24 << 20));     // 48 MiB  [8192][3072]
  u16* vTb   = (u16*)(ws + (size_t)(72 << 20));     // 16 MiB  [64][64][2048]
  u16* abuf  = xb;  // alias: xb dead after GEMM1   // total 88 MiB

  cvt_f32_bf16<<<4096, 256, 0, stream>>>(x, xb, (B_ * N_ * DIM_) / 8);
  transp_w<<<dim3(QKV3_ / 32, DIM_ / 32), 256, 0, stream>>>(w_qkv, wqkvT, DIM_, QKV3_);
  transp_w<<<dim3(DIM_ / 32, INNER_ / 32), 256, 0, stream>>>(w_out, woutT, INNER_, DIM_);
  gemm_bt<0><<<(B_ * N_ / 128) * (QKV3_ / 128), 256, 0, stream>>>(
      xb, wqkvT, qkv, nullptr, B_ * N_, QKV3_, DIM_);
  transp_v<<<dim3(N_ / 32, DH_ / 32, B_ * HEADS_), 256, 0, stream>>>(qkv, vTb);
  attn_fwd<<<B_ * HEADS_ * (N_ / 64), 256, 0, stream>>>(qkv, vTb, abuf);
  gemm_bt<1><<<(B_ * N_ / 128) * (DIM_ / 128), 256, 0, stream>>>(
      abuf, woutT, out, b_out, B_ * N_, DIM_, INNER_);
}

// Round 2
// 311.416 us; speedup vs baseline: 1.8419x; 1.8419x over previous
//
#include <hip/hip_runtime.h>

typedef unsigned short u16;
typedef __bf16 bf16_t;
typedef bf16_t bf16x8 __attribute__((ext_vector_type(8)));
typedef float f32x4 __attribute__((ext_vector_type(4)));
typedef u16 u16x8 __attribute__((ext_vector_type(8)));

#define B_     4
#define N_     2048
#define DIM_   1024
#define HEADS_ 16
#define DH_    64
#define INNER_ 1024
#define QKV3_  3072
#define SCALE_ 0.125f

__device__ __forceinline__ u16 f2bf(float f) {
  union { float f; unsigned u; } v; v.f = f;
  unsigned r = v.u + 0x7FFFu + ((v.u >> 16) & 1u);
  return (u16)(r >> 16);
}

// ---------------- x fp32 -> bf16 (vectorized, G13) ----------------
__global__ __launch_bounds__(256) void cvt_f32_bf16(const float* __restrict__ in,
                                                    u16* __restrict__ out, int n8) {
  int i = blockIdx.x * 256 + threadIdx.x;
  if (i < n8) {
    const float4* p = (const float4*)(in + (size_t)i * 8);
    float4 a = p[0], b = p[1];
    u16x8 o;
    o[0] = f2bf(a.x); o[1] = f2bf(a.y); o[2] = f2bf(a.z); o[3] = f2bf(a.w);
    o[4] = f2bf(b.x); o[5] = f2bf(b.y); o[6] = f2bf(b.z); o[7] = f2bf(b.w);
    *(u16x8*)(out + (size_t)i * 8) = o;
  }
}

// ---------------- w [K][N] fp32 -> wT [N][K] bf16 ----------------
__global__ __launch_bounds__(256) void transp_w(const float* __restrict__ in,
                                                u16* __restrict__ out, int Kd, int Nd) {
  __shared__ float t[32][33];
  int n0 = blockIdx.x * 32, k0 = blockIdx.y * 32;
  int tx = threadIdx.x & 31, ty = threadIdx.x >> 5;   // 256 threads: 32x8
#pragma unroll
  for (int i = 0; i < 4; i++)
    t[ty + i * 8][tx] = in[(size_t)(k0 + ty + i * 8) * Nd + n0 + tx];
  __syncthreads();
#pragma unroll
  for (int i = 0; i < 4; i++)
    out[(size_t)(n0 + ty + i * 8) * Kd + k0 + tx] = f2bf(t[tx][ty + i * 8]);
}

// ---------------- V slice of qkv -> vT [b,h,d,n] bf16 ----------------
__global__ __launch_bounds__(256) void transp_v(const u16* __restrict__ qkv,
                                                u16* __restrict__ vT) {
  __shared__ u16 t[32][33];
  int bh = blockIdx.z; int b = bh >> 4, h = bh & 15;
  int n0 = blockIdx.x * 32, d0 = blockIdx.y * 32;
  int tx = threadIdx.x & 31, ty = threadIdx.x >> 5;
#pragma unroll
  for (int i = 0; i < 4; i++)
    t[ty + i * 8][tx] =
        qkv[(size_t)(b * N_ + n0 + ty + i * 8) * QKV3_ + 2 * INNER_ + h * DH_ + d0 + tx];
  __syncthreads();
#pragma unroll
  for (int i = 0; i < 4; i++)
    vT[((size_t)bh * DH_ + d0 + ty + i * 8) * N_ + n0 + tx] = t[tx][ty + i * 8];
}

// ---------------- GEMM: C[M][N] = A[M][K](bf16) @ BT[N][K](bf16)^T ----------------
template <int F32OUT>
__global__ __launch_bounds__(256) void gemm_bt(const u16* __restrict__ A,
                                               const u16* __restrict__ BT,
                                               void* __restrict__ Cp,
                                               const float* __restrict__ bias,
                                               int M, int N, int K) {
  __shared__ alignas(16) u16 ldsA[128 * 64];
  __shared__ alignas(16) u16 ldsB[128 * 64];
  const int tid = threadIdx.x;
  const int lane = tid & 63, wid = tid >> 6;
  const int l16 = lane & 15, lg = lane >> 4;
  const int ntiles = N >> 7;
  const int tm = blockIdx.x / ntiles, tn = blockIdx.x % ntiles;
  const int m0 = tm << 7, n0 = tn << 7;
  const int wr = wid >> 1, wc = wid & 1;

  f32x4 acc[4][4];
#pragma unroll
  for (int i = 0; i < 4; i++)
#pragma unroll
    for (int j = 0; j < 4; j++) acc[i][j] = f32x4{0.f, 0.f, 0.f, 0.f};

  for (int k0 = 0; k0 < K; k0 += 64) {
#pragma unroll
    for (int i = 0; i < 4; i++) {
      int c = i * 256 + tid;
      int row = c >> 3, slot = c & 7;
      uint4 va = *(const uint4*)(A  + (size_t)(m0 + row) * K + k0 + slot * 8);
      uint4 vb = *(const uint4*)(BT + (size_t)(n0 + row) * K + k0 + slot * 8);
      int off = row * 128 + ((slot * 16) ^ ((row & 7) << 4));
      *(uint4*)((char*)ldsA + off) = va;
      *(uint4*)((char*)ldsB + off) = vb;
    }
    __syncthreads();

    bf16x8 bf[4][2];
#pragma unroll
    for (int n = 0; n < 4; n++) {
      int row = wc * 64 + n * 16 + l16;
      int rb = row * 128, swz = (row & 7) << 4;
      bf[n][0] = *(const bf16x8*)((char*)ldsB + rb + ((lg * 16) ^ swz));
      bf[n][1] = *(const bf16x8*)((char*)ldsB + rb + ((64 + lg * 16) ^ swz));
    }
#pragma unroll
    for (int mm = 0; mm < 4; mm++) {
      int row = wr * 64 + mm * 16 + l16;
      int rb = row * 128, swz = (row & 7) << 4;
      bf16x8 af0 = *(const bf16x8*)((char*)ldsA + rb + ((lg * 16) ^ swz));
      bf16x8 af1 = *(const bf16x8*)((char*)ldsA + rb + ((64 + lg * 16) ^ swz));
#pragma unroll
      for (int n = 0; n < 4; n++) {
        acc[mm][n] = __builtin_amdgcn_mfma_f32_16x16x32_bf16(af0, bf[n][0], acc[mm][n], 0, 0, 0);
        acc[mm][n] = __builtin_amdgcn_mfma_f32_16x16x32_bf16(af1, bf[n][1], acc[mm][n], 0, 0, 0);
      }
    }
    __syncthreads();
  }

#pragma unroll
  for (int mm = 0; mm < 4; mm++) {
#pragma unroll
    for (int n = 0; n < 4; n++) {
      int row = m0 + wr * 64 + mm * 16 + lg * 4;
      int col = n0 + wc * 64 + n * 16 + l16;
#pragma unroll
      for (int j = 0; j < 4; j++) {
        if (F32OUT)
          ((float*)Cp)[(size_t)(row + j) * N + col] = acc[mm][n][j] + bias[col];
        else
          ((u16*)Cp)[(size_t)(row + j) * N + col] = f2bf(acc[mm][n][j]);
      }
    }
  }
}

// ---------------- Flash attention (v2) ----------------
// grid: 1024 blocks (XCD-chunk-swizzled), 256 threads = 4 waves.
// Q-tile 128 rows/block, wave owns 32 q-rows (2 m-frags).
// K/V staged in LDS (shared, XOR-swizzled), DOUBLE-BUFFERED, one barrier/kt.
// Scale folded into Q (0.125 = 2^-3, exact in bf16).
__global__ __launch_bounds__(256) void attn_fwd(const u16* __restrict__ qkv,
                                                const u16* __restrict__ vT,
                                                u16* __restrict__ abuf) {
  __shared__ alignas(16) u16 ldsK[2][64 * 64];
  __shared__ alignas(16) u16 ldsV[2][64 * 64];
  __shared__ alignas(16) u16 plds[4][32 * 64];

  const int tid = threadIdx.x;
  const int lane = tid & 63, wid = tid >> 6;
  const int l16 = lane & 15, lg = lane >> 4;

  int bid = blockIdx.x;
  bid = (bid & 7) * 128 + (bid >> 3);   // T1 chunked XCD swizzle (1024%8==0)
  const int bh = bid >> 4, qt = bid & 15;
  const int b = bh >> 4, h = bh & 15;
  const int q0 = qt * 128 + wid * 32;

  // ---- Q fragments, scale folded in (exact: 2^-3) ----
  bf16x8 qf[2][2];
#pragma unroll
  for (int mm = 0; mm < 2; mm++) {
    const u16* qrow = qkv + (size_t)(b * N_ + q0 + mm * 16 + l16) * QKV3_ + h * DH_;
    bf16x8 t0 = *(const bf16x8*)(qrow + lg * 8);
    bf16x8 t1 = *(const bf16x8*)(qrow + 32 + lg * 8);
#pragma unroll
    for (int i = 0; i < 8; i++) {
      t0[i] = (bf16_t)((float)t0[i] * SCALE_);
      t1[i] = (bf16_t)((float)t1[i] * SCALE_);
    }
    qf[mm][0] = t0; qf[mm][1] = t1;
  }

  // ---- staging geometry: 256 thr, each stages rows (srow, srow+32) of K and V ----
  const int srow = tid >> 3, sslot = tid & 7;
  const u16* ksrc = qkv + (size_t)(b * N_ + srow) * QKV3_ + INNER_ + h * DH_ + sslot * 8;
  const u16* vsrc = vT + ((size_t)bh * DH_ + srow) * N_ + sslot * 8;
  const int wo0 = srow * 128 + ((sslot * 16) ^ ((srow & 7) << 4));
  const int wo1 = wo0 + 32 * 128;      // (srow+32)&7 == srow&7

  char* pwave = (char*)&plds[wid][0];

  float mrow[2][4], lrow[2][4];
  f32x4 acc[2][4];
#pragma unroll
  for (int mm = 0; mm < 2; mm++)
#pragma unroll
    for (int j = 0; j < 4; j++) { mrow[mm][j] = -1e30f; lrow[mm][j] = 0.f; }
#pragma unroll
  for (int mm = 0; mm < 2; mm++)
#pragma unroll
    for (int d = 0; d < 4; d++) acc[mm][d] = f32x4{0.f, 0.f, 0.f, 0.f};

  // ---- prologue: stage kt=0 into buffer 0 ----
  {
    uint4 k0 = *(const uint4*)(ksrc);
    uint4 k1 = *(const uint4*)(ksrc + (size_t)32 * QKV3_);
    uint4 v0 = *(const uint4*)(vsrc);
    uint4 v1 = *(const uint4*)(vsrc + 32 * N_);
    *(uint4*)((char*)&ldsK[0][0] + wo0) = k0;
    *(uint4*)((char*)&ldsK[0][0] + wo1) = k1;
    *(uint4*)((char*)&ldsV[0][0] + wo0) = v0;
    *(uint4*)((char*)&ldsV[0][0] + wo1) = v1;
  }

  const int NT = N_ / 64;
  for (int kt = 0; kt < NT; ++kt) {
    const int cur = kt & 1;
    // T14 issue-early: global loads for kt+1
    uint4 kr0, kr1, vr0, vr1;
    if (kt < NT - 1) {
      const u16* kp = ksrc + (size_t)(kt + 1) * 64 * QKV3_;
      const u16* vp = vsrc + (kt + 1) * 64;
      kr0 = *(const uint4*)(kp);
      kr1 = *(const uint4*)(kp + (size_t)32 * QKV3_);
      vr0 = *(const uint4*)(vp);
      vr1 = *(const uint4*)(vp + 32 * N_);
    }
    __syncthreads();   // buf[cur] writes visible; prev reads of buf[cur^1] done

    const char* Kb = (const char*)&ldsK[cur][0];
    const char* Vb = (const char*)&ldsV[cur][0];

    // ---- QK^T: s[mm][kc] over 64 keys ----
    f32x4 s[2][4];
#pragma unroll
    for (int kc = 0; kc < 4; kc++) {
      int r = kc * 16 + l16;
      const char* rb = Kb + r * 128;
      int swz = (r & 7) << 4;
      bf16x8 kf0 = *(const bf16x8*)(rb + ((lg * 16) ^ swz));
      bf16x8 kf1 = *(const bf16x8*)(rb + ((64 + lg * 16) ^ swz));
#pragma unroll
      for (int mm = 0; mm < 2; mm++) {
        f32x4 c = f32x4{0.f, 0.f, 0.f, 0.f};
        c = __builtin_amdgcn_mfma_f32_16x16x32_bf16(qf[mm][0], kf0, c, 0, 0, 0);
        c = __builtin_amdgcn_mfma_f32_16x16x32_bf16(qf[mm][1], kf1, c, 0, 0, 0);
        s[mm][kc] = c;
      }
    }

    // ---- online softmax ----
    float alpha[2][4], psum[2][4];
#pragma unroll
    for (int mm = 0; mm < 2; mm++)
#pragma unroll
      for (int j = 0; j < 4; j++) {
        float t = fmaxf(fmaxf(s[mm][0][j], s[mm][1][j]), fmaxf(s[mm][2][j], s[mm][3][j]));
#pragma unroll
        for (int off = 1; off < 16; off <<= 1) t = fmaxf(t, __shfl_xor(t, off));
        float mn = fmaxf(mrow[mm][j], t);
        alpha[mm][j] = __expf(mrow[mm][j] - mn);
        mrow[mm][j] = mn;
        psum[mm][j] = 0.f;
      }
    // P = exp(s - m) -> bf16 swizzled LDS (per-wave)
#pragma unroll
    for (int mm = 0; mm < 2; mm++)
#pragma unroll
      for (int kc = 0; kc < 4; kc++)
#pragma unroll
        for (int j = 0; j < 4; j++) {
          float p = __expf(s[mm][kc][j] - mrow[mm][j]);
          psum[mm][j] += p;
          int r = mm * 16 + lg * 4 + j;
          int off = r * 128 + (((kc * 16 + l16) * 2) ^ ((r & 7) << 4));
          *(u16*)(pwave + off) = f2bf(p);
        }
#pragma unroll
    for (int mm = 0; mm < 2; mm++)
#pragma unroll
      for (int j = 0; j < 4; j++) {
        float t = psum[mm][j];
#pragma unroll
        for (int off = 1; off < 16; off <<= 1) t += __shfl_xor(t, off);
        lrow[mm][j] = lrow[mm][j] * alpha[mm][j] + t;
      }
#pragma unroll
    for (int mm = 0; mm < 2; mm++)
#pragma unroll
      for (int d = 0; d < 4; d++)
#pragma unroll
        for (int j = 0; j < 4; j++) acc[mm][d][j] *= alpha[mm][j];

    // ---- PV ----
    bf16x8 pa[2][2];
#pragma unroll
    for (int mm = 0; mm < 2; mm++) {
      int r = mm * 16 + l16;
      int swz = (r & 7) << 4;
#pragma unroll
      for (int ks = 0; ks < 2; ks++)
        pa[mm][ks] = *(const bf16x8*)(pwave + r * 128 + ((ks * 64 + lg * 16) ^ swz));
    }
#pragma unroll
    for (int dd = 0; dd < 4; dd++) {
      int r = dd * 16 + l16;
      const char* rb = Vb + r * 128;
      int swz = (r & 7) << 4;
      bf16x8 vf0 = *(const bf16x8*)(rb + ((lg * 16) ^ swz));
      bf16x8 vf1 = *(const bf16x8*)(rb + ((64 + lg * 16) ^ swz));
#pragma unroll
      for (int mm = 0; mm < 2; mm++) {
        acc[mm][dd] = __builtin_amdgcn_mfma_f32_16x16x32_bf16(pa[mm][0], vf0, acc[mm][dd], 0, 0, 0);
        acc[mm][dd] = __builtin_amdgcn_mfma_f32_16x16x32_bf16(pa[mm][1], vf1, acc[mm][dd], 0, 0, 0);
      }
    }

    // T14 write-late: stage kt+1 into buf[cur^1]
    if (kt < NT - 1) {
      char* Kn = (char*)&ldsK[cur ^ 1][0];
      char* Vn = (char*)&ldsV[cur ^ 1][0];
      *(uint4*)(Kn + wo0) = kr0;
      *(uint4*)(Kn + wo1) = kr1;
      *(uint4*)(Vn + wo0) = vr0;
      *(uint4*)(Vn + wo1) = vr1;
    }
  }

  // ---- epilogue ----
#pragma unroll
  for (int mm = 0; mm < 2; mm++)
#pragma unroll
    for (int j = 0; j < 4; j++) {
      float inv = 1.f / lrow[mm][j];
      size_t row = (size_t)(b * N_ + q0 + mm * 16 + lg * 4 + j);
#pragma unroll
      for (int dd = 0; dd < 4; dd++)
        abuf[row * INNER_ + h * DH_ + dd * 16 + l16] = f2bf(acc[mm][dd][j] * inv);
    }
}

extern "C" void kernel_launch(void* const* d_in, const int* in_sizes, int n_in,
                              void* d_out, int out_size, void* d_ws, size_t ws_size,
                              hipStream_t stream) {
  const float* x     = (const float*)d_in[0];
  const float* w_qkv = (const float*)d_in[1];
  const float* w_out = (const float*)d_in[2];
  const float* b_out = (const float*)d_in[3];
  float* out = (float*)d_out;

  char* ws = (char*)d_ws;
  u16* xb    = (u16*)(ws);                          // 16 MiB  [8192][1024]
  u16* wqkvT = (u16*)(ws + (size_t)(16 << 20));     //  6 MiB  [3072][1024]
  u16* woutT = (u16*)(ws + (size_t)(22 << 20));     //  2 MiB  [1024][1024]
  u16* qkv   = (u16*)(ws + (size_t)(24 << 20));     // 48 MiB  [8192][3072]
  u16* vTb   = (u16*)(ws + (size_t)(72 << 20));     // 16 MiB  [64][64][2048]
  u16* abuf  = xb;  // alias: xb dead after GEMM1

  cvt_f32_bf16<<<4096, 256, 0, stream>>>(x, xb, (B_ * N_ * DIM_) / 8);
  transp_w<<<dim3(QKV3_ / 32, DIM_ / 32), 256, 0, stream>>>(w_qkv, wqkvT, DIM_, QKV3_);
  transp_w<<<dim3(DIM_ / 32, INNER_ / 32), 256, 0, stream>>>(w_out, woutT, INNER_, DIM_);
  gemm_bt<0><<<(B_ * N_ / 128) * (QKV3_ / 128), 256, 0, stream>>>(
      xb, wqkvT, qkv, nullptr, B_ * N_, QKV3_, DIM_);
  transp_v<<<dim3(N_ / 32, DH_ / 32, B_ * HEADS_), 256, 0, stream>>>(qkv, vTb);
  attn_fwd<<<1024, 256, 0, stream>>>(qkv, vTb, abuf);
  gemm_bt<1><<<(B_ * N_ / 128) * (DIM_ / 128), 256, 0, stream>>>(
      abuf, woutT, out, b_out, B_ * N_, DIM_, INNER_);
}

// Round 3
// 232.619 us; speedup vs baseline: 2.4658x; 1.3387x over previous
//
#include <hip/hip_runtime.h>

typedef unsigned short u16;
typedef __bf16 bf16_t;
typedef bf16_t bf16x8 __attribute__((ext_vector_type(8)));
typedef float f32x4 __attribute__((ext_vector_type(4)));
typedef u16 u16x8 __attribute__((ext_vector_type(8)));
typedef u16 u16x4 __attribute__((ext_vector_type(4)));

#define B_     4
#define N_     2048
#define DIM_   1024
#define HEADS_ 16
#define DH_    64
#define INNER_ 1024
#define QKV3_  3072
#define SCALE_ 0.125f

__device__ __forceinline__ u16 f2bf(float f) {
  union { float f; unsigned u; } v; v.f = f;
  unsigned r = v.u + 0x7FFFu + ((v.u >> 16) & 1u);
  return (u16)(r >> 16);
}
__device__ __forceinline__ u16 bfbits(float f) {
  bf16_t b = (bf16_t)f;               // RNE; compiler pairs into v_cvt_pk_bf16_f32
  return __builtin_bit_cast(u16, b);
}

// ---------------- x fp32 -> bf16 (vectorized, G13) ----------------
__global__ __launch_bounds__(256) void cvt_f32_bf16(const float* __restrict__ in,
                                                    u16* __restrict__ out, int n8) {
  int i = blockIdx.x * 256 + threadIdx.x;
  if (i < n8) {
    const float4* p = (const float4*)(in + (size_t)i * 8);
    float4 a = p[0], b = p[1];
    u16x8 o;
    o[0] = f2bf(a.x); o[1] = f2bf(a.y); o[2] = f2bf(a.z); o[3] = f2bf(a.w);
    o[4] = f2bf(b.x); o[5] = f2bf(b.y); o[6] = f2bf(b.z); o[7] = f2bf(b.w);
    *(u16x8*)(out + (size_t)i * 8) = o;
  }
}

// ---------------- w [K][N] fp32 -> wT [N][K] bf16 ----------------
__global__ __launch_bounds__(256) void transp_w(const float* __restrict__ in,
                                                u16* __restrict__ out, int Kd, int Nd) {
  __shared__ float t[32][33];
  int n0 = blockIdx.x * 32, k0 = blockIdx.y * 32;
  int tx = threadIdx.x & 31, ty = threadIdx.x >> 5;   // 256 threads: 32x8
#pragma unroll
  for (int i = 0; i < 4; i++)
    t[ty + i * 8][tx] = in[(size_t)(k0 + ty + i * 8) * Nd + n0 + tx];
  __syncthreads();
#pragma unroll
  for (int i = 0; i < 4; i++)
    out[(size_t)(n0 + ty + i * 8) * Kd + k0 + tx] = f2bf(t[tx][ty + i * 8]);
}

// ---------------- V slice of qkv -> vT [b,h,d,n] bf16 ----------------
__global__ __launch_bounds__(256) void transp_v(const u16* __restrict__ qkv,
                                                u16* __restrict__ vT) {
  __shared__ u16 t[32][33];
  int bh = blockIdx.z; int b = bh >> 4, h = bh & 15;
  int n0 = blockIdx.x * 32, d0 = blockIdx.y * 32;
  int tx = threadIdx.x & 31, ty = threadIdx.x >> 5;
#pragma unroll
  for (int i = 0; i < 4; i++)
    t[ty + i * 8][tx] =
        qkv[(size_t)(b * N_ + n0 + ty + i * 8) * QKV3_ + 2 * INNER_ + h * DH_ + d0 + tx];
  __syncthreads();
#pragma unroll
  for (int i = 0; i < 4; i++)
    vT[((size_t)bh * DH_ + d0 + ty + i * 8) * N_ + n0 + tx] = t[tx][ty + i * 8];
}

// ---------------- GEMM: C[M][N] = A[M][K](bf16) @ BT[N][K](bf16)^T ----------------
template <int F32OUT>
__global__ __launch_bounds__(256) void gemm_bt(const u16* __restrict__ A,
                                               const u16* __restrict__ BT,
                                               void* __restrict__ Cp,
                                               const float* __restrict__ bias,
                                               int M, int N, int K) {
  __shared__ alignas(16) u16 ldsA[128 * 64];
  __shared__ alignas(16) u16 ldsB[128 * 64];
  const int tid = threadIdx.x;
  const int lane = tid & 63, wid = tid >> 6;
  const int l16 = lane & 15, lg = lane >> 4;
  const int ntiles = N >> 7;
  const int tm = blockIdx.x / ntiles, tn = blockIdx.x % ntiles;
  const int m0 = tm << 7, n0 = tn << 7;
  const int wr = wid >> 1, wc = wid & 1;

  f32x4 acc[4][4];
#pragma unroll
  for (int i = 0; i < 4; i++)
#pragma unroll
    for (int j = 0; j < 4; j++) acc[i][j] = f32x4{0.f, 0.f, 0.f, 0.f};

  for (int k0 = 0; k0 < K; k0 += 64) {
#pragma unroll
    for (int i = 0; i < 4; i++) {
      int c = i * 256 + tid;
      int row = c >> 3, slot = c & 7;
      uint4 va = *(const uint4*)(A  + (size_t)(m0 + row) * K + k0 + slot * 8);
      uint4 vb = *(const uint4*)(BT + (size_t)(n0 + row) * K + k0 + slot * 8);
      int off = row * 128 + ((slot * 16) ^ ((row & 7) << 4));
      *(uint4*)((char*)ldsA + off) = va;
      *(uint4*)((char*)ldsB + off) = vb;
    }
    __syncthreads();

    bf16x8 bf[4][2];
#pragma unroll
    for (int n = 0; n < 4; n++) {
      int row = wc * 64 + n * 16 + l16;
      int rb = row * 128, swz = (row & 7) << 4;
      bf[n][0] = *(const bf16x8*)((char*)ldsB + rb + ((lg * 16) ^ swz));
      bf[n][1] = *(const bf16x8*)((char*)ldsB + rb + ((64 + lg * 16) ^ swz));
    }
#pragma unroll
    for (int mm = 0; mm < 4; mm++) {
      int row = wr * 64 + mm * 16 + l16;
      int rb = row * 128, swz = (row & 7) << 4;
      bf16x8 af0 = *(const bf16x8*)((char*)ldsA + rb + ((lg * 16) ^ swz));
      bf16x8 af1 = *(const bf16x8*)((char*)ldsA + rb + ((64 + lg * 16) ^ swz));
#pragma unroll
      for (int n = 0; n < 4; n++) {
        acc[mm][n] = __builtin_amdgcn_mfma_f32_16x16x32_bf16(af0, bf[n][0], acc[mm][n], 0, 0, 0);
        acc[mm][n] = __builtin_amdgcn_mfma_f32_16x16x32_bf16(af1, bf[n][1], acc[mm][n], 0, 0, 0);
      }
    }
    __syncthreads();
  }

#pragma unroll
  for (int mm = 0; mm < 4; mm++) {
#pragma unroll
    for (int n = 0; n < 4; n++) {
      int row = m0 + wr * 64 + mm * 16 + lg * 4;
      int col = n0 + wc * 64 + n * 16 + l16;
#pragma unroll
      for (int j = 0; j < 4; j++) {
        if (F32OUT)
          ((float*)Cp)[(size_t)(row + j) * N + col] = acc[mm][n][j] + bias[col];
        else
          ((u16*)Cp)[(size_t)(row + j) * N + col] = f2bf(acc[mm][n][j]);
      }
    }
  }
}

// ---------------- Flash attention (v3: swapped QK^T, lane-local softmax) ----------------
// grid: 1024 blocks (XCD-chunk-swizzled), 256 threads = 4 waves.
// Q-tile 128 rows/block, wave owns 32 q-rows (mm=0,1), KVBLK=64.
// S^T = mfma(K,Q): lane owns q=l16, keys kc*16+lg*4+j -> in-lane max/sum + 2 shfl.
// O^T = mfma(Vt,P): stats (m,l,alpha) are one lane-local scalar per mm.
// T13 defer-max: skip rescale unless row max grew by >8.
__global__ __launch_bounds__(256) void attn_fwd(const u16* __restrict__ qkv,
                                                const u16* __restrict__ vT,
                                                u16* __restrict__ abuf) {
  __shared__ alignas(16) u16 ldsK[2][64 * 64];
  __shared__ alignas(16) u16 ldsV[2][64 * 64];
  __shared__ alignas(16) u16 plds[4][32 * 64];

  const int tid = threadIdx.x;
  const int lane = tid & 63, wid = tid >> 6;
  const int l16 = lane & 15, lg = lane >> 4;

  int bid = blockIdx.x;
  bid = (bid & 7) * 128 + (bid >> 3);   // T1 chunked XCD swizzle (1024%8==0)
  const int bh = bid >> 4, qt = bid & 15;
  const int b = bh >> 4, h = bh & 15;
  const int q0 = qt * 128 + wid * 32;

  // ---- Q fragments, scale folded in (exact: 2^-3) ----
  bf16x8 qf[2][2];
#pragma unroll
  for (int mm = 0; mm < 2; mm++) {
    const u16* qrow = qkv + (size_t)(b * N_ + q0 + mm * 16 + l16) * QKV3_ + h * DH_;
    bf16x8 t0 = *(const bf16x8*)(qrow + lg * 8);
    bf16x8 t1 = *(const bf16x8*)(qrow + 32 + lg * 8);
#pragma unroll
    for (int i = 0; i < 8; i++) {
      t0[i] = (bf16_t)((float)t0[i] * SCALE_);
      t1[i] = (bf16_t)((float)t1[i] * SCALE_);
    }
    qf[mm][0] = t0; qf[mm][1] = t1;
  }

  // ---- staging geometry: 256 thr, each stages rows (srow, srow+32) of K and V ----
  const int srow = tid >> 3, sslot = tid & 7;
  const u16* ksrc = qkv + (size_t)(b * N_ + srow) * QKV3_ + INNER_ + h * DH_ + sslot * 8;
  const u16* vsrc = vT + ((size_t)bh * DH_ + srow) * N_ + sslot * 8;
  const int wo0 = srow * 128 + ((sslot * 16) ^ ((srow & 7) << 4));
  const int wo1 = wo0 + 32 * 128;      // (srow+32)&7 == srow&7

  char* pwave = (char*)&plds[wid][0];

  float mrow[2], lrow[2];
  f32x4 acc[2][4];   // acc[mm][dd] = O^T: d = dd*16+lg*4+j, q = mm*16+l16
#pragma unroll
  for (int mm = 0; mm < 2; mm++) { mrow[mm] = -1e30f; lrow[mm] = 0.f; }
#pragma unroll
  for (int mm = 0; mm < 2; mm++)
#pragma unroll
    for (int d = 0; d < 4; d++) acc[mm][d] = f32x4{0.f, 0.f, 0.f, 0.f};

  // ---- prologue: stage kt=0 into buffer 0 ----
  {
    uint4 k0 = *(const uint4*)(ksrc);
    uint4 k1 = *(const uint4*)(ksrc + (size_t)32 * QKV3_);
    uint4 v0 = *(const uint4*)(vsrc);
    uint4 v1 = *(const uint4*)(vsrc + 32 * N_);
    *(uint4*)((char*)&ldsK[0][0] + wo0) = k0;
    *(uint4*)((char*)&ldsK[0][0] + wo1) = k1;
    *(uint4*)((char*)&ldsV[0][0] + wo0) = v0;
    *(uint4*)((char*)&ldsV[0][0] + wo1) = v1;
  }

  const int NT = N_ / 64;
  for (int kt = 0; kt < NT; ++kt) {
    const int cur = kt & 1;
    // T14 issue-early: global loads for kt+1
    uint4 kr0, kr1, vr0, vr1;
    if (kt < NT - 1) {
      const u16* kp = ksrc + (size_t)(kt + 1) * 64 * QKV3_;
      const u16* vp = vsrc + (kt + 1) * 64;
      kr0 = *(const uint4*)(kp);
      kr1 = *(const uint4*)(kp + (size_t)32 * QKV3_);
      vr0 = *(const uint4*)(vp);
      vr1 = *(const uint4*)(vp + 32 * N_);
    }
    __syncthreads();   // buf[cur] writes visible; prev reads of buf[cur^1] done

    const char* Kb = (const char*)&ldsK[cur][0];
    const char* Vb = (const char*)&ldsV[cur][0];

    // ---- swapped QK^T: s[mm][kc] = S^T[key=kc*16+lg*4+j][q=l16] ----
    f32x4 s[2][4];
#pragma unroll
    for (int kc = 0; kc < 4; kc++) {
      int r = kc * 16 + l16;
      const char* rb = Kb + r * 128;
      int swz = (r & 7) << 4;
      bf16x8 kf0 = *(const bf16x8*)(rb + ((lg * 16) ^ swz));
      bf16x8 kf1 = *(const bf16x8*)(rb + ((64 + lg * 16) ^ swz));
#pragma unroll
      for (int mm = 0; mm < 2; mm++) {
        f32x4 c = f32x4{0.f, 0.f, 0.f, 0.f};
        c = __builtin_amdgcn_mfma_f32_16x16x32_bf16(kf0, qf[mm][0], c, 0, 0, 0);
        c = __builtin_amdgcn_mfma_f32_16x16x32_bf16(kf1, qf[mm][1], c, 0, 0, 0);
        s[mm][kc] = c;
      }
    }

    // ---- lane-local online softmax ----
#pragma unroll
    for (int mm = 0; mm < 2; mm++) {
      f32x4 mv0, mv1;
#pragma unroll
      for (int j = 0; j < 4; j++) {
        mv0[j] = fmaxf(s[mm][0][j], s[mm][1][j]);
        mv1[j] = fmaxf(s[mm][2][j], s[mm][3][j]);
      }
      float t = fmaxf(fmaxf(fmaxf(mv0[0], mv0[1]), fmaxf(mv0[2], mv0[3])),
                      fmaxf(fmaxf(mv1[0], mv1[1]), fmaxf(mv1[2], mv1[3])));
      t = fmaxf(t, __shfl_xor(t, 16));
      t = fmaxf(t, __shfl_xor(t, 32));
      float mn = fmaxf(mrow[mm], t);
      // T13 defer-max: only rescale when some row grew by > 8
      if (__ballot(mn - mrow[mm] > 8.f)) {
        float alpha = __expf(mrow[mm] - mn);
        mrow[mm] = mn;
        lrow[mm] *= alpha;
#pragma unroll
        for (int dd = 0; dd < 4; dd++)
#pragma unroll
          for (int j = 0; j < 4; j++) acc[mm][dd][j] *= alpha;
      }
      // P = exp(s - m): in-lane, pack 4 bf16 -> one 8B LDS store per kc
      float psum = 0.f;
      int r = mm * 16 + l16;
      int swz = (r & 7) << 4;
#pragma unroll
      for (int kc = 0; kc < 4; kc++) {
        float p0 = __expf(s[mm][kc][0] - mrow[mm]);
        float p1 = __expf(s[mm][kc][1] - mrow[mm]);
        float p2 = __expf(s[mm][kc][2] - mrow[mm]);
        float p3 = __expf(s[mm][kc][3] - mrow[mm]);
        psum += (p0 + p1) + (p2 + p3);
        u16x4 w;
        w[0] = bfbits(p0); w[1] = bfbits(p1); w[2] = bfbits(p2); w[3] = bfbits(p3);
        *(u16x4*)(pwave + r * 128 + ((kc * 32 + lg * 8) ^ swz)) = w;
      }
      psum += __shfl_xor(psum, 16);
      psum += __shfl_xor(psum, 32);
      lrow[mm] += psum;
    }

    // ---- PV as O^T = mfma(Vt rows, P rows) ----
    bf16x8 pa[2][2];
#pragma unroll
    for (int mm = 0; mm < 2; mm++) {
      int r = mm * 16 + l16;
      int swz = (r & 7) << 4;
#pragma unroll
      for (int ks = 0; ks < 2; ks++)
        pa[mm][ks] = *(const bf16x8*)(pwave + r * 128 + ((ks * 64 + lg * 16) ^ swz));
    }
#pragma unroll
    for (int dd = 0; dd < 4; dd++) {
      int r = dd * 16 + l16;
      const char* rb = Vb + r * 128;
      int swz = (r & 7) << 4;
      bf16x8 vf0 = *(const bf16x8*)(rb + ((lg * 16) ^ swz));
      bf16x8 vf1 = *(const bf16x8*)(rb + ((64 + lg * 16) ^ swz));
#pragma unroll
      for (int mm = 0; mm < 2; mm++) {
        acc[mm][dd] = __builtin_amdgcn_mfma_f32_16x16x32_bf16(vf0, pa[mm][0], acc[mm][dd], 0, 0, 0);
        acc[mm][dd] = __builtin_amdgcn_mfma_f32_16x16x32_bf16(vf1, pa[mm][1], acc[mm][dd], 0, 0, 0);
      }
    }

    // T14 write-late: stage kt+1 into buf[cur^1]
    if (kt < NT - 1) {
      char* Kn = (char*)&ldsK[cur ^ 1][0];
      char* Vn = (char*)&ldsV[cur ^ 1][0];
      *(uint4*)(Kn + wo0) = kr0;
      *(uint4*)(Kn + wo1) = kr1;
      *(uint4*)(Vn + wo0) = vr0;
      *(uint4*)(Vn + wo1) = vr1;
    }
  }

  // ---- epilogue: O[q][d] = acc^T / l ; packed 8B stores ----
#pragma unroll
  for (int mm = 0; mm < 2; mm++) {
    float inv = 1.f / lrow[mm];
    size_t row = (size_t)(b * N_ + q0 + mm * 16 + l16);
#pragma unroll
    for (int dd = 0; dd < 4; dd++) {
      u16x4 w;
#pragma unroll
      for (int j = 0; j < 4; j++) w[j] = bfbits(acc[mm][dd][j] * inv);
      *(u16x4*)(abuf + row * INNER_ + h * DH_ + dd * 16 + lg * 4) = w;
    }
  }
}

extern "C" void kernel_launch(void* const* d_in, const int* in_sizes, int n_in,
                              void* d_out, int out_size, void* d_ws, size_t ws_size,
                              hipStream_t stream) {
  const float* x     = (const float*)d_in[0];
  const float* w_qkv = (const float*)d_in[1];
  const float* w_out = (const float*)d_in[2];
  const float* b_out = (const float*)d_in[3];
  float* out = (float*)d_out;

  char* ws = (char*)d_ws;
  u16* xb    = (u16*)(ws);                          // 16 MiB  [8192][1024]
  u16* wqkvT = (u16*)(ws + (size_t)(16 << 20));     //  6 MiB  [3072][1024]
  u16* woutT = (u16*)(ws + (size_t)(22 << 20));     //  2 MiB  [1024][1024]
  u16* qkv   = (u16*)(ws + (size_t)(24 << 20));     // 48 MiB  [8192][3072]
  u16* vTb   = (u16*)(ws + (size_t)(72 << 20));     // 16 MiB  [64][64][2048]
  u16* abuf  = xb;  // alias: xb dead after GEMM1

  cvt_f32_bf16<<<4096, 256, 0, stream>>>(x, xb, (B_ * N_ * DIM_) / 8);
  transp_w<<<dim3(QKV3_ / 32, DIM_ / 32), 256, 0, stream>>>(w_qkv, wqkvT, DIM_, QKV3_);
  transp_w<<<dim3(DIM_ / 32, INNER_ / 32), 256, 0, stream>>>(w_out, woutT, INNER_, DIM_);
  gemm_bt<0><<<(B_ * N_ / 128) * (QKV3_ / 128), 256, 0, stream>>>(
      xb, wqkvT, qkv, nullptr, B_ * N_, QKV3_, DIM_);
  transp_v<<<dim3(N_ / 32, DH_ / 32, B_ * HEADS_), 256, 0, stream>>>(qkv, vTb);
  attn_fwd<<<1024, 256, 0, stream>>>(qkv, vTb, abuf);
  gemm_bt<1><<<(B_ * N_ / 128) * (DIM_ / 128), 256, 0, stream>>>(
      abuf, woutT, out, b_out, B_ * N_, DIM_, INNER_);
}

// Round 4
// 210.761 us; speedup vs baseline: 2.7215x; 1.1037x over previous
//
#include <hip/hip_runtime.h>

typedef unsigned short u16;
typedef __bf16 bf16_t;
typedef bf16_t bf16x8 __attribute__((ext_vector_type(8)));
typedef float f32x4 __attribute__((ext_vector_type(4)));
typedef u16 u16x8 __attribute__((ext_vector_type(8)));
typedef u16 u16x4 __attribute__((ext_vector_type(4)));

#define B_     4
#define N_     2048
#define DIM_   1024
#define HEADS_ 16
#define DH_    64
#define INNER_ 1024
#define QKV3_  3072
#define SCALE_ 0.125f
#define LOG2E_ 1.44269504089f

__device__ __forceinline__ u16 f2bf(float f) {
  union { float f; unsigned u; } v; v.f = f;
  unsigned r = v.u + 0x7FFFu + ((v.u >> 16) & 1u);
  return (u16)(r >> 16);
}
__device__ __forceinline__ u16 bfbits(float f) {
  bf16_t b = (bf16_t)f;               // RNE; pairs into v_cvt_pk_bf16_f32
  return __builtin_bit_cast(u16, b);
}

#if __has_builtin(__builtin_amdgcn_exp2f)
#define EXP2F(x) __builtin_amdgcn_exp2f(x)
#else
#define EXP2F(x) __expf((x) * 0.69314718056f)
#endif

// async global->LDS, 16B per lane; LDS dest = wave-uniform base + lane*16
typedef __attribute__((address_space(1))) const unsigned int ga_u32;
typedef __attribute__((address_space(3))) unsigned int ls_u32;
__device__ __forceinline__ void gload16(const void* g, void* l) {
  __builtin_amdgcn_global_load_lds((ga_u32*)g, (ls_u32*)l, 16, 0, 0);
}

// ---------------- x fp32 -> bf16 (vectorized, G13) ----------------
__global__ __launch_bounds__(256) void cvt_f32_bf16(const float* __restrict__ in,
                                                    u16* __restrict__ out, int n8) {
  int i = blockIdx.x * 256 + threadIdx.x;
  if (i < n8) {
    const float4* p = (const float4*)(in + (size_t)i * 8);
    float4 a = p[0], b = p[1];
    u16x8 o;
    o[0] = f2bf(a.x); o[1] = f2bf(a.y); o[2] = f2bf(a.z); o[3] = f2bf(a.w);
    o[4] = f2bf(b.x); o[5] = f2bf(b.y); o[6] = f2bf(b.z); o[7] = f2bf(b.w);
    *(u16x8*)(out + (size_t)i * 8) = o;
  }
}

// ---------------- w [K][N] fp32 -> wT [N][K] bf16 ----------------
__global__ __launch_bounds__(256) void transp_w(const float* __restrict__ in,
                                                u16* __restrict__ out, int Kd, int Nd) {
  __shared__ float t[32][33];
  int n0 = blockIdx.x * 32, k0 = blockIdx.y * 32;
  int tx = threadIdx.x & 31, ty = threadIdx.x >> 5;   // 256 threads: 32x8
#pragma unroll
  for (int i = 0; i < 4; i++)
    t[ty + i * 8][tx] = in[(size_t)(k0 + ty + i * 8) * Nd + n0 + tx];
  __syncthreads();
#pragma unroll
  for (int i = 0; i < 4; i++)
    out[(size_t)(n0 + ty + i * 8) * Kd + k0 + tx] = f2bf(t[tx][ty + i * 8]);
}

// ---------------- V slice of qkv -> vT [b,h,d,n] bf16 ----------------
__global__ __launch_bounds__(256) void transp_v(const u16* __restrict__ qkv,
                                                u16* __restrict__ vT) {
  __shared__ u16 t[32][33];
  int bh = blockIdx.z; int b = bh >> 4, h = bh & 15;
  int n0 = blockIdx.x * 32, d0 = blockIdx.y * 32;
  int tx = threadIdx.x & 31, ty = threadIdx.x >> 5;
#pragma unroll
  for (int i = 0; i < 4; i++)
    t[ty + i * 8][tx] =
        qkv[(size_t)(b * N_ + n0 + ty + i * 8) * QKV3_ + 2 * INNER_ + h * DH_ + d0 + tx];
  __syncthreads();
#pragma unroll
  for (int i = 0; i < 4; i++)
    vT[((size_t)bh * DH_ + d0 + ty + i * 8) * N_ + n0 + tx] = t[tx][ty + i * 8];
}

// ---------------- GEMM: C[M][N] = A[M][K](bf16) @ BT[N][K](bf16)^T ----------------
// 128x128 tile, BK=64, 4 waves (2x2), 16x16x32 MFMA.
// Staging via global_load_lds(16B) with pre-swizzled SOURCE (m173/m201):
// LDS content at (row, slot) holds source slot (slot ^ (row&7)); reads XOR the same.
template <int F32OUT>
__global__ __launch_bounds__(256) void gemm_bt(const u16* __restrict__ A,
                                               const u16* __restrict__ BT,
                                               void* __restrict__ Cp,
                                               const float* __restrict__ bias,
                                               int M, int N, int K) {
  __shared__ alignas(16) u16 ldsA[128 * 64];
  __shared__ alignas(16) u16 ldsB[128 * 64];
  const int tid = threadIdx.x;
  const int lane = tid & 63, wid = tid >> 6;
  const int l16 = lane & 15, lg = lane >> 4;
  const int ntiles = N >> 7;
  const int tm = blockIdx.x / ntiles, tn = blockIdx.x % ntiles;
  const int m0 = tm << 7, n0 = tn << 7;
  const int wr = wid >> 1, wc = wid & 1;

  // staging: wave wid covers rows 32*wid .. 32*wid+31 (4 gloads of 8 rows each)
  const int srow_in = lane >> 3;            // 0..7 row within 8-row group
  const int soff = ((lane & 7) ^ srow_in) * 8;  // pre-swizzled source slot (elems)

  f32x4 acc[4][4];
#pragma unroll
  for (int i = 0; i < 4; i++)
#pragma unroll
    for (int j = 0; j < 4; j++) acc[i][j] = f32x4{0.f, 0.f, 0.f, 0.f};

  for (int k0 = 0; k0 < K; k0 += 64) {
#pragma unroll
    for (int i = 0; i < 4; i++) {
      const int rbase = wid * 32 + i * 8;
      gload16(A  + (size_t)(m0 + rbase + srow_in) * K + k0 + soff,
              (char*)ldsA + rbase * 128);
      gload16(BT + (size_t)(n0 + rbase + srow_in) * K + k0 + soff,
              (char*)ldsB + rbase * 128);
    }
    __syncthreads();   // drains vmcnt + syncs

    bf16x8 bf[4][2];
#pragma unroll
    for (int n = 0; n < 4; n++) {
      int row = wc * 64 + n * 16 + l16;
      int rb = row * 128, swz = (row & 7) << 4;
      bf[n][0] = *(const bf16x8*)((char*)ldsB + rb + ((lg * 16) ^ swz));
      bf[n][1] = *(const bf16x8*)((char*)ldsB + rb + ((64 + lg * 16) ^ swz));
    }
#pragma unroll
    for (int mm = 0; mm < 4; mm++) {
      int row = wr * 64 + mm * 16 + l16;
      int rb = row * 128, swz = (row & 7) << 4;
      bf16x8 af0 = *(const bf16x8*)((char*)ldsA + rb + ((lg * 16) ^ swz));
      bf16x8 af1 = *(const bf16x8*)((char*)ldsA + rb + ((64 + lg * 16) ^ swz));
#pragma unroll
      for (int n = 0; n < 4; n++) {
        acc[mm][n] = __builtin_amdgcn_mfma_f32_16x16x32_bf16(af0, bf[n][0], acc[mm][n], 0, 0, 0);
        acc[mm][n] = __builtin_amdgcn_mfma_f32_16x16x32_bf16(af1, bf[n][1], acc[mm][n], 0, 0, 0);
      }
    }
    __syncthreads();
  }

#pragma unroll
  for (int mm = 0; mm < 4; mm++) {
#pragma unroll
    for (int n = 0; n < 4; n++) {
      int row = m0 + wr * 64 + mm * 16 + lg * 4;
      int col = n0 + wc * 64 + n * 16 + l16;
#pragma unroll
      for (int j = 0; j < 4; j++) {
        if (F32OUT)
          ((float*)Cp)[(size_t)(row + j) * N + col] = acc[mm][n][j] + bias[col];
        else
          ((u16*)Cp)[(size_t)(row + j) * N + col] = f2bf(acc[mm][n][j]);
      }
    }
  }
}

// ---------------- Flash attention (v4) ----------------
// 512 blocks (XCD-swizzled) x 512 threads (8 waves). QBLK=256, wave owns 32 q-rows.
// K/V double-buffered in LDS via global_load_lds with pre-swizzled source.
// Swapped QK^T (lane-local softmax), exp2+fma, T13 defer-max, T5 setprio.
// LDS: 32KB K/V dbuf + 32KB plds = 64KB -> 2 blocks/CU (no tail at 512 blocks).
__global__ __launch_bounds__(512, 4) void attn_fwd(const u16* __restrict__ qkv,
                                                   const u16* __restrict__ vT,
                                                   u16* __restrict__ abuf) {
  __shared__ alignas(16) u16 ldsK[2][64 * 64];
  __shared__ alignas(16) u16 ldsV[2][64 * 64];
  __shared__ alignas(16) u16 plds[8][32 * 64];

  const int tid = threadIdx.x;
  const int lane = tid & 63, wid = tid >> 6;   // 8 waves
  const int l16 = lane & 15, lg = lane >> 4;

  int bid = blockIdx.x;
  bid = (bid & 7) * 64 + (bid >> 3);   // T1 chunked XCD swizzle (512%8==0)
  const int bh = bid >> 3, qt = bid & 7;
  const int b = bh >> 4, h = bh & 15;
  const int q0 = qt * 256 + wid * 32;

  // ---- Q fragments, scale folded in (exact: 2^-3) ----
  bf16x8 qf[2][2];
#pragma unroll
  for (int mm = 0; mm < 2; mm++) {
    const u16* qrow = qkv + (size_t)(b * N_ + q0 + mm * 16 + l16) * QKV3_ + h * DH_;
    bf16x8 t0 = *(const bf16x8*)(qrow + lg * 8);
    bf16x8 t1 = *(const bf16x8*)(qrow + 32 + lg * 8);
#pragma unroll
    for (int i = 0; i < 8; i++) {
      t0[i] = (bf16_t)((float)t0[i] * SCALE_);
      t1[i] = (bf16_t)((float)t1[i] * SCALE_);
    }
    qf[mm][0] = t0; qf[mm][1] = t1;
  }

  // ---- staging geometry: wave wid stages rows 8*wid..8*wid+7 of K and V ----
  const int srow = (wid << 3) + (lane >> 3);          // 0..63
  const int sswz = (lane & 7) ^ (srow & 7);           // pre-swizzled source slot
  const u16* ksrc = qkv + (size_t)(b * N_ + srow) * QKV3_ + INNER_ + h * DH_ + sswz * 8;
  const u16* vsrc = vT + ((size_t)bh * DH_ + srow) * N_ + sswz * 8;
  const int sdst = wid << 10;                         // wave-uniform byte offset

  char* pwave = (char*)&plds[wid][0];

  float mrow[2], lrow[2];
  f32x4 acc[2][4];   // O^T: d = dd*16+lg*4+j, q = mm*16+l16
#pragma unroll
  for (int mm = 0; mm < 2; mm++) { mrow[mm] = -1e30f; lrow[mm] = 0.f; }
#pragma unroll
  for (int mm = 0; mm < 2; mm++)
#pragma unroll
    for (int d = 0; d < 4; d++) acc[mm][d] = f32x4{0.f, 0.f, 0.f, 0.f};

  // ---- prologue: stage kt=0 into buffer 0 ----
  gload16(ksrc, (char*)&ldsK[0][0] + sdst);
  gload16(vsrc, (char*)&ldsV[0][0] + sdst);
  __syncthreads();

  const int NT = N_ / 64;
  for (int kt = 0; kt < NT; ++kt) {
    const int cur = kt & 1;
    // prefetch kt+1 into buf[cur^1] (async; drained at end-of-iter barrier)
    if (kt < NT - 1) {
      gload16(ksrc + (size_t)(kt + 1) * 64 * QKV3_, (char*)&ldsK[cur ^ 1][0] + sdst);
      gload16(vsrc + (kt + 1) * 64, (char*)&ldsV[cur ^ 1][0] + sdst);
    }

    const char* Kb = (const char*)&ldsK[cur][0];
    const char* Vb = (const char*)&ldsV[cur][0];

    // ---- swapped QK^T: s[mm][kc] = S^T[key=kc*16+lg*4+j][q=l16] ----
    f32x4 s[2][4];
    __builtin_amdgcn_s_setprio(1);
#pragma unroll
    for (int kc = 0; kc < 4; kc++) {
      int r = kc * 16 + l16;
      const char* rb = Kb + r * 128;
      int swz = (r & 7) << 4;
      bf16x8 kf0 = *(const bf16x8*)(rb + ((lg * 16) ^ swz));
      bf16x8 kf1 = *(const bf16x8*)(rb + ((64 + lg * 16) ^ swz));
#pragma unroll
      for (int mm = 0; mm < 2; mm++) {
        f32x4 c = f32x4{0.f, 0.f, 0.f, 0.f};
        c = __builtin_amdgcn_mfma_f32_16x16x32_bf16(kf0, qf[mm][0], c, 0, 0, 0);
        c = __builtin_amdgcn_mfma_f32_16x16x32_bf16(kf1, qf[mm][1], c, 0, 0, 0);
        s[mm][kc] = c;
      }
    }
    __builtin_amdgcn_s_setprio(0);

    // ---- lane-local online softmax (exp2 + fma) ----
#pragma unroll
    for (int mm = 0; mm < 2; mm++) {
      float t = fmaxf(fmaxf(fmaxf(s[mm][0][0], s[mm][0][1]), fmaxf(s[mm][0][2], s[mm][0][3])),
                      fmaxf(fmaxf(s[mm][1][0], s[mm][1][1]), fmaxf(s[mm][1][2], s[mm][1][3])));
      float u = fmaxf(fmaxf(fmaxf(s[mm][2][0], s[mm][2][1]), fmaxf(s[mm][2][2], s[mm][2][3])),
                      fmaxf(fmaxf(s[mm][3][0], s[mm][3][1]), fmaxf(s[mm][3][2], s[mm][3][3])));
      t = fmaxf(t, u);
      t = fmaxf(t, __shfl_xor(t, 16));
      t = fmaxf(t, __shfl_xor(t, 32));
      float mn = fmaxf(mrow[mm], t);
      // T13 defer-max: only rescale when some row grew by > 8
      if (__ballot(mn - mrow[mm] > 8.f)) {
        float alpha = __expf(mrow[mm] - mn);
        mrow[mm] = mn;
        lrow[mm] *= alpha;
#pragma unroll
        for (int dd = 0; dd < 4; dd++)
#pragma unroll
          for (int j = 0; j < 4; j++) acc[mm][dd][j] *= alpha;
      }
      const float nm2 = -mrow[mm] * LOG2E_;
      float psum = 0.f;
      int r = mm * 16 + l16;
      int swz = (r & 7) << 4;
#pragma unroll
      for (int kc = 0; kc < 4; kc++) {
        float p0 = EXP2F(__builtin_fmaf(s[mm][kc][0], LOG2E_, nm2));
        float p1 = EXP2F(__builtin_fmaf(s[mm][kc][1], LOG2E_, nm2));
        float p2 = EXP2F(__builtin_fmaf(s[mm][kc][2], LOG2E_, nm2));
        float p3 = EXP2F(__builtin_fmaf(s[mm][kc][3], LOG2E_, nm2));
        psum += (p0 + p1) + (p2 + p3);
        u16x4 w;
        w[0] = bfbits(p0); w[1] = bfbits(p1); w[2] = bfbits(p2); w[3] = bfbits(p3);
        *(u16x4*)(pwave + r * 128 + ((kc * 32 + lg * 8) ^ swz)) = w;
      }
      psum += __shfl_xor(psum, 16);
      psum += __shfl_xor(psum, 32);
      lrow[mm] += psum;
    }

    // ---- PV as O^T = mfma(Vt rows, P rows) ----
    bf16x8 pa[2][2];
#pragma unroll
    for (int mm = 0; mm < 2; mm++) {
      int r = mm * 16 + l16;
      int swz = (r & 7) << 4;
#pragma unroll
      for (int ks = 0; ks < 2; ks++)
        pa[mm][ks] = *(const bf16x8*)(pwave + r * 128 + ((ks * 64 + lg * 16) ^ swz));
    }
    __builtin_amdgcn_s_setprio(1);
#pragma unroll
    for (int dd = 0; dd < 4; dd++) {
      int r = dd * 16 + l16;
      const char* rb = Vb + r * 128;
      int swz = (r & 7) << 4;
      bf16x8 vf0 = *(const bf16x8*)(rb + ((lg * 16) ^ swz));
      bf16x8 vf1 = *(const bf16x8*)(rb + ((64 + lg * 16) ^ swz));
#pragma unroll
      for (int mm = 0; mm < 2; mm++) {
        acc[mm][dd] = __builtin_amdgcn_mfma_f32_16x16x32_bf16(vf0, pa[mm][0], acc[mm][dd], 0, 0, 0);
        acc[mm][dd] = __builtin_amdgcn_mfma_f32_16x16x32_bf16(vf1, pa[mm][1], acc[mm][dd], 0, 0, 0);
      }
    }
    __builtin_amdgcn_s_setprio(0);

    __syncthreads();   // drains prefetch vmcnt + syncs buffer swap
  }

  // ---- epilogue: O[q][d] = acc^T / l ; packed 8B stores ----
#pragma unroll
  for (int mm = 0; mm < 2; mm++) {
    float inv = 1.f / lrow[mm];
    size_t row = (size_t)(b * N_ + q0 + mm * 16 + l16);
#pragma unroll
    for (int dd = 0; dd < 4; dd++) {
      u16x4 w;
#pragma unroll
      for (int j = 0; j < 4; j++) w[j] = bfbits(acc[mm][dd][j] * inv);
      *(u16x4*)(abuf + row * INNER_ + h * DH_ + dd * 16 + lg * 4) = w;
    }
  }
}

extern "C" void kernel_launch(void* const* d_in, const int* in_sizes, int n_in,
                              void* d_out, int out_size, void* d_ws, size_t ws_size,
                              hipStream_t stream) {
  const float* x     = (const float*)d_in[0];
  const float* w_qkv = (const float*)d_in[1];
  const float* w_out = (const float*)d_in[2];
  const float* b_out = (const float*)d_in[3];
  float* out = (float*)d_out;

  char* ws = (char*)d_ws;
  u16* xb    = (u16*)(ws);                          // 16 MiB  [8192][1024]
  u16* wqkvT = (u16*)(ws + (size_t)(16 << 20));     //  6 MiB  [3072][1024]
  u16* woutT = (u16*)(ws + (size_t)(22 << 20));     //  2 MiB  [1024][1024]
  u16* qkv   = (u16*)(ws + (size_t)(24 << 20));     // 48 MiB  [8192][3072]
  u16* vTb   = (u16*)(ws + (size_t)(72 << 20));     // 16 MiB  [64][64][2048]
  u16* abuf  = xb;  // alias: xb dead after GEMM1

  cvt_f32_bf16<<<4096, 256, 0, stream>>>(x, xb, (B_ * N_ * DIM_) / 8);
  transp_w<<<dim3(QKV3_ / 32, DIM_ / 32), 256, 0, stream>>>(w_qkv, wqkvT, DIM_, QKV3_);
  transp_w<<<dim3(DIM_ / 32, INNER_ / 32), 256, 0, stream>>>(w_out, woutT, INNER_, DIM_);
  gemm_bt<0><<<(B_ * N_ / 128) * (QKV3_ / 128), 256, 0, stream>>>(
      xb, wqkvT, qkv, nullptr, B_ * N_, QKV3_, DIM_);
  transp_v<<<dim3(N_ / 32, DH_ / 32, B_ * HEADS_), 256, 0, stream>>>(qkv, vTb);
  attn_fwd<<<512, 512, 0, stream>>>(qkv, vTb, abuf);
  gemm_bt<1><<<(B_ * N_ / 128) * (DIM_ / 128), 256, 0, stream>>>(
      abuf, woutT, out, b_out, B_ * N_, DIM_, INNER_);
}